// Round 18
// baseline (352.884 us; speedup 1.0000x reference)
//
#include <hip/hip_runtime.h>

typedef unsigned short u16;
typedef short bfrag __attribute__((ext_vector_type(8)));   // 8 bf16 = one K=32 MFMA A/B frag
typedef float ffrag __attribute__((ext_vector_type(4)));   // MFMA C/D frag
typedef u16 u16x4 __attribute__((ext_vector_type(4)));
typedef float f4 __attribute__((ext_vector_type(4)));

#define MFMA16(a,b,c)  __builtin_amdgcn_mfma_f32_16x16x32_bf16((a),(b),(c),0,0,0)

#define WAITV(N) do { asm volatile("s_waitcnt vmcnt(" #N ")" ::: "memory"); \
                      __builtin_amdgcn_sched_barrier(0); } while(0)
#define RBAR()   do { __builtin_amdgcn_s_barrier(); \
                      __builtin_amdgcn_sched_barrier(0); } while(0)

// B=2, C=256, H=64, W=512 ; PIX=65536 ; NROW=B*H=128 ; max_w=int(512*0.26)=133 -> |i-j|<=132
// QK-fold: S = x1·M·x2^T + c2[p'] (+row-const terms that cancel in softmax),
//          M[c,d] = sum_o Qw[o,c]Kw[o,d], g[d] = sum_o Qb[o]Kw[o,d], c2 = x_k-side · g.

__device__ __forceinline__ u16 f2bf(float f){
  union { float f; unsigned int i; } cv; cv.f = f;
  unsigned int x = cv.i;
  return (u16)((x + 0x7fffu + ((x >> 16) & 1u)) >> 16);  // RNE
}
__device__ __forceinline__ float bf2f(u16 u){
  union { unsigned int i; float f; } cv;
  cv.i = ((unsigned int)u) << 16;
  return cv.f;
}
__device__ __forceinline__ unsigned cvtpk(float lo, float hi){
  unsigned r; asm("v_cvt_pk_bf16_f32 %0, %1, %2" : "=v"(r) : "v"(lo), "v"(hi)); return r;
}
__device__ __forceinline__ bfrag ldb(const u16* p){
  bfrag v; __builtin_memcpy(&v, p, 16); return v;
}
__device__ __forceinline__ void gload_lds16(const u16* g, u16* l){
  __builtin_amdgcn_global_load_lds(
      (const __attribute__((address_space(1))) unsigned int*)g,
      (__attribute__((address_space(3))) unsigned int*)l, 16, 0, 0);
}

// ---------- weights fp32 -> bf16 ----------
__global__ __launch_bounds__(256) void k_wcvt(const float* __restrict__ qw, const float* __restrict__ kw,
                                              const float* __restrict__ vw, const float* __restrict__ ww,
                                              u16* __restrict__ out){
  int t = blockIdx.x*256 + threadIdx.x;
  out[t]        = f2bf(qw[t]);
  out[t+65536]  = f2bf(kw[t]);
  out[t+131072] = f2bf(vw[t]);
  out[t+196608] = f2bf(ww[t]);
}

// ---------- g[d] = sum_o Qb[o]*Kw[o,d] (fp32 sources) ----------
__global__ __launch_bounds__(256) void k_g(const float* __restrict__ Qb, const float* __restrict__ Kw,
                                           float* __restrict__ g){
  int t = threadIdx.x;
  float sm = 0.f;
  #pragma unroll 8
  for (int o=0;o<256;++o) sm += Qb[o]*Kw[o*256 + t];
  g[t] = sm;
}

// ---------- wm[d*256+c] = M[c,d] = sum_o Qw[o,c]*Kw[o,d] ----------
__global__ __launch_bounds__(256) void k_mg(const u16* __restrict__ wb, u16* __restrict__ wm){
  int c = blockIdx.x, t = threadIdx.x;
  float sm = 0.f;
  #pragma unroll 8
  for (int o=0;o<256;++o) sm += bf2f(wb[o*256 + c]) * bf2f(wb[65536 + o*256 + t]);
  wm[t*256 + c] = f2bf(sm);
}

// ---------- x (B,C,H,W) fp32 -> xr (p, c) bf16 ; fused c2 partials (x·g) ----------
__global__ __launch_bounds__(256) void k_xpose(const float* __restrict__ x1, const float* __restrict__ x2,
                                               u16* __restrict__ xr1, u16* __restrict__ xr2,
                                               const float* __restrict__ g, float* __restrict__ c2p){
  const float* x = blockIdx.z ? x2 : x1;
  u16* xr = blockIdx.z ? xr2 : xr1;
  __shared__ float T[64][65];
  __shared__ float c2l[4][64];
  int t = threadIdx.x;
  int p0 = blockIdx.x*64, c0 = blockIdx.y*64;
  int b = p0 >> 15, q0 = p0 & 32767;
  float part0=0.f, part1=0.f, part2=0.f, part3=0.f;
  #pragma unroll
  for (int it=0; it<4; ++it){
    int cc = it*16 + (t>>4);
    int pi = (t&15)*4;
    ffrag v; __builtin_memcpy(&v, x + ((size_t)(b*256 + c0 + cc))*32768 + q0 + pi, 16);
    T[cc][pi+0]=v[0]; T[cc][pi+1]=v[1]; T[cc][pi+2]=v[2]; T[cc][pi+3]=v[3];
    float gc = g[c0 + cc];
    part0 += v[0]*gc; part1 += v[1]*gc; part2 += v[2]*gc; part3 += v[3]*gc;
  }
  part0 += __shfl_xor(part0,16,64); part0 += __shfl_xor(part0,32,64);
  part1 += __shfl_xor(part1,16,64); part1 += __shfl_xor(part1,32,64);
  part2 += __shfl_xor(part2,16,64); part2 += __shfl_xor(part2,32,64);
  part3 += __shfl_xor(part3,16,64); part3 += __shfl_xor(part3,32,64);
  int w = t>>6, lane = t&63;
  if (lane < 16){
    c2l[w][lane*4+0]=part0; c2l[w][lane*4+1]=part1;
    c2l[w][lane*4+2]=part2; c2l[w][lane*4+3]=part3;
  }
  __syncthreads();
  int pi = t>>2, cj0 = (t&3)*16;
  u16 tmp[16];
  #pragma unroll
  for (int j=0;j<16;++j) tmp[j] = f2bf(T[cj0+j][pi]);
  __builtin_memcpy(xr + (size_t)(p0+pi)*256 + c0 + cj0, tmp, 32);
  if (t < 64){
    float smm = c2l[0][t] + c2l[1][t] + c2l[2][t] + c2l[3][t];
    c2p[(((size_t)blockIdx.y*2 + blockIdx.z)<<16) + p0 + t] = smm;
  }
}

// ---------- reduce 4 c2 quarters -> c2all[s][p] ----------
__global__ __launch_bounds__(256) void k_c2red(const float* __restrict__ c2p, float* __restrict__ c2all){
  int s = blockIdx.y;
  int row = blockIdx.x*256 + threadIdx.x;
  float smm = c2p[((size_t)(0*2+s)<<16) + row] + c2p[((size_t)(1*2+s)<<16) + row]
            + c2p[((size_t)(2*2+s)<<16) + row] + c2p[((size_t)(3*2+s)<<16) + row];
  c2all[s*65536 + row] = smm;
}

// ---------- tile staging: NI*4KB, rows of 128B (64 k-cols bf16), XOR-swizzled ----------
template<int NI>
__device__ __forceinline__ void stageT(const u16* __restrict__ src, int row0, int k0,
                                       u16* lds, int wid, int l){
  #pragma unroll
  for (int rr=0; rr<NI; ++rr){
    int off = rr*4096 + wid*1024 + l*16;        // byte offset in tile
    int row = off>>7, inb = off&127;
    int srcb = inb ^ ((row&7)<<4);              // pre-swizzled source (rule 21)
    gload_lds16(src + (size_t)(row0+row)*256 + k0 + (srcb>>1),
                lds + ((rr*4096 + wid*1024)>>1));
  }
}

// ---------- fused XM/V conv: 128p x 64o tiles, BK=64, 3 blk/CU; V-BN partials fused ----------
__global__ __launch_bounds__(256, 3) void k_qkv(const u16* __restrict__ xr1, const u16* __restrict__ xr2,
    const u16* __restrict__ wb, const u16* __restrict__ wm,
    const float* __restrict__ vb,
    u16* __restrict__ XM1, u16* __restrict__ V1,
    u16* __restrict__ XM2, u16* __restrict__ V2,
    float* __restrict__ vpsum, float* __restrict__ vpsq){
  __shared__ __align__(16) u16 As[2][8192];     // 2 x 16KB (128 rows)
  __shared__ __align__(16) u16 Bs[2][4096];     // 2 x 8KB  (64 rows)
  int id = blockIdx.x;
  int xcd = id & 7, j = id >> 3;                // 1024 per XCD
  int pl = j >> 4, v = j & 15;                  // 64 p-tiles x 16 variants per XCD
  int ptile = xcd*64 + pl;
  int ot = v & 3, r = v >> 2;
  int wgtV = r >> 1, s = r & 1;                 // wgtV: 0=XM, 1=V
  const u16* A = s ? xr2 : xr1;
  const u16* W = wgtV ? (wb + 131072) : wm;

  int t = threadIdx.x, wid = t>>6, l = t&63, lr = l&15, lg = l>>4;
  int p0 = ptile*128, o0 = ot*64;
  int wr = wid*32;
  int swz = (lr&7)<<4;

  stageT<4>(A, p0, 0,  As[0], wid, l);
  stageT<2>(W, o0, 0,  Bs[0], wid, l);
  stageT<4>(A, p0, 64, As[1], wid, l);
  stageT<2>(W, o0, 64, Bs[1], wid, l);

  const ffrag fz = {0.f,0.f,0.f,0.f};
  ffrag acc[2][4];
  #pragma unroll
  for (int i=0;i<2;++i){ acc[i][0]=fz; acc[i][1]=fz; acc[i][2]=fz; acc[i][3]=fz; }

  #pragma unroll
  for (int ks=0; ks<4; ++ks){
    if (ks < 3) { WAITV(6); } else { WAITV(0); }
    RBAR();
    const u16* as = As[ks&1];
    const u16* bs = Bs[ks&1];
    #pragma unroll
    for (int kc=0; kc<2; ++kc){
      int colb = (kc*64 + lg*16) ^ swz;
      bfrag af[2], bf[4];
      #pragma unroll
      for (int mt=0; mt<2; ++mt)
        af[mt] = ldb(as + (((wr + mt*16 + lr)*128 + colb)>>1));
      #pragma unroll
      for (int nt=0; nt<4; ++nt)
        bf[nt] = ldb(bs + (((nt*16 + lr)*128 + colb)>>1));
      if (!wgtV){
        #pragma unroll
        for (int mt=0; mt<2; ++mt)
          #pragma unroll
          for (int nt=0; nt<4; ++nt)
            acc[mt][nt] = MFMA16(bf[nt], af[mt], acc[mt][nt]);   // D[o][p] (swapped)
      } else {
        #pragma unroll
        for (int mt=0; mt<2; ++mt)
          #pragma unroll
          for (int nt=0; nt<4; ++nt)
            acc[mt][nt] = MFMA16(af[mt], bf[nt], acc[mt][nt]);   // D[p][o]
      }
    }
    RBAR();
    if (ks < 2){
      stageT<4>(A, p0, (ks+2)*64, As[ks&1], wid, l);
      stageT<2>(W, o0, (ks+2)*64, Bs[ks&1], wid, l);
    }
  }

  if (!wgtV){
    u16* op = s ? XM2 : XM1;                    // no bias (row-terms cancel in softmax)
    #pragma unroll
    for (int nt=0; nt<4; ++nt){
      int ob = o0 + nt*16 + lg*4;
      #pragma unroll
      for (int mt=0; mt<2; ++mt){
        int p = p0 + wr + mt*16 + lr;
        u16x4 vv;
        #pragma unroll
        for (int rr=0;rr<4;++rr) vv[rr] = f2bf(acc[mt][nt][rr]);
        *reinterpret_cast<u16x4*>(op + (size_t)p*256 + ob) = vv;
      }
    }
  } else {
    u16* Vt = s ? V2 : V1;
    float pvv[4], qvv[4];
    #pragma unroll
    for (int nt=0; nt<4; ++nt){ pvv[nt]=0.f; qvv[nt]=0.f; }
    #pragma unroll
    for (int nt=0; nt<4; ++nt){
      int oo = o0 + nt*16 + lr;
      float bsc = vb[oo];
      #pragma unroll
      for (int mt=0; mt<2; ++mt){
        int pr = p0 + wr + mt*16 + lg*4;
        int n = pr >> 9, w0 = pr & 511;
        u16x4 vv;
        #pragma unroll
        for (int rr=0;rr<4;++rr){
          float val = acc[mt][nt][rr] + bsc;
          vv[rr] = f2bf(val);
          pvv[nt] += val; qvv[nt] += val*val;
        }
        *reinterpret_cast<u16x4*>(Vt + ((size_t)(n*256 + oo))*512 + w0) = vv;
      }
    }
    #pragma unroll
    for (int nt=0; nt<4; ++nt){
      float sv = pvv[nt], sq = qvv[nt];
      sv += __shfl_xor(sv,16,64); sv += __shfl_xor(sv,32,64);
      sq += __shfl_xor(sq,16,64); sq += __shfl_xor(sq,32,64);
      if (lg==0){
        int oo = o0 + nt*16 + lr;
        size_t idx = (((size_t)(s*256 + oo))<<11) + (ptile<<2) + wid;
        vpsum[idx] = sv; vpsq[idx] = sq;
      }
    }
  }
}

// ---------- V BN stats stage 2 (reduces qkv's fused partials, 2048 per channel) ----------
__global__ __launch_bounds__(256) void k_vstat2(const float* __restrict__ ps, const float* __restrict__ pq,
                                                const float* __restrict__ g, const float* __restrict__ be,
                                                float* __restrict__ aVall, float* __restrict__ bVall){
  int c = blockIdx.x, s = blockIdx.y, t = threadIdx.x;
  const float* psb = ps + (((size_t)(s*256 + c))<<11);
  const float* pqb = pq + (((size_t)(s*256 + c))<<11);
  float sm=0.f, sq=0.f;
  #pragma unroll
  for (int j2=0;j2<8;++j2){ sm += psb[t + j2*256]; sq += pqb[t + j2*256]; }
  __shared__ float rs[256], rq[256];
  rs[t]=sm; rq[t]=sq; __syncthreads();
  for (int st=128; st>0; st>>=1){ if (t<st){ rs[t]+=rs[t+st]; rq[t]+=rq[t+st]; } __syncthreads(); }
  if (t==0){
    float mean = rs[0]*(1.f/65536.f);
    float var  = rq[0]*(1.f/65536.f) - mean*mean;
    float aa = g[c]*rsqrtf(var + 1e-5f);
    aVall[s*256+c]=aa; bVall[s*256+c]=be[c]-aa*mean;
  }
}

// ---------- staging helpers for k_attn (8-wave block: 1 KB per wave per call) ----------
__device__ __forceinline__ void stageK8(const u16* Kn, u16* kb, int kt, int wid, int l){
  int off = wid*1024 + l*16;                        // byte offset in 8KB tile
  int row = off>>9, inb = off&511;
  int src = inb ^ ((row&7)<<4);                     // pre-swizzled source
  gload_lds16(Kn + (size_t)(kt*16+row)*256 + (src>>1), kb + (off>>1));
}
// V tile 16KB: channel c holds its 32-k chunk at byte c*64; 16B slot swizzled by (c>>1)&3
__device__ __forceinline__ void stageV8(const u16* Vn, u16* vb, int k0, int wid, int l){
  #pragma unroll
  for (int it=0; it<2; ++it){
    int off = wid*2048 + it*1024 + l*16;            // byte offset in 16KB tile
    int crow = off>>6, slot = (off>>4)&3;
    int kk = slot ^ ((crow>>1)&3);                  // pre-swizzled source chunk
    gload_lds16(Vn + (size_t)crow*512 + k0 + (kk<<3), vb + (off>>1));
  }
}

// ---------- banded attention v10: QBLK=128, 8 waves, 16 waves/CU; v7 step body ----------
__global__ __launch_bounds__(512, 2) void k_attn(
    const u16* __restrict__ XM1, const u16* __restrict__ xr2, const u16* __restrict__ V2,
    const u16* __restrict__ XM2, const u16* __restrict__ xr1, const u16* __restrict__ V1,
    const float* __restrict__ aVall, const float* __restrict__ bVall,
    const float* __restrict__ c2all,
    u16* __restrict__ O1, u16* __restrict__ O2){
  __shared__ __align__(16) u16 KP[2][8192];          // 2 x 16KB: K tile-pair dbuf
  __shared__ __align__(16) u16 VBs[2][8192];         // 2 x 16KB: V chunk dbuf
  int t = threadIdx.x, wid = t>>6, l = t&63, lr = l&15, lg = l>>4;
  int id = blockIdx.x;
  int s = id >> 9;
  int r0 = id & 511;
  int xcd = r0 & 7, s5 = r0 >> 3;                    // s5 in 0..63
  int qb = s5 & 3, n = (xcd<<4) | (s5>>2);
  const u16* Q = s ? XM2 : XM1;
  const u16* K = s ? xr1 : xr2;
  const u16* V = s ? V1 : V2;
  const float* aV = aVall + (s ? 0 : 256);
  const float* bV = bVall + (s ? 0 : 256);
  const float* c2k = c2all + ((s^1)<<16) + n*512;    // c2 of the K-side stream
  u16* O = s ? O2 : O1;

  int q0 = qb*128, q0w = q0 + wid*16;
  int lo = q0 - 132; if (lo < 0) lo = 0;
  int hi = q0 + 259; if (hi > 511) hi = 511;
  int KTLO = (lo>>4) & ~1;                           // even
  int KTHI = (hi>>4) | 1;                            // odd
  int nsteps = (KTHI - KTLO + 2) >> 1;               // 9..13 steps of 32 k-cols

  const u16* Kn = K + (size_t)n*131072;
  const u16* Vn = V + (size_t)n*131072;

  // Q frags + step-0 c2; drain so vmcnt literals below are exact
  bfrag qa[8];
  const u16* Qrow = Q + ((size_t)(n*512 + q0w + lr))*256 + lg*8;
  #pragma unroll
  for (int ks=0; ks<8; ++ks) qa[ks] = ldb(Qrow + ks*32);
  f4 c2A, c2B, c2An, c2Bn;
  {
    int colb0 = KTLO*16 + lg*4;
    c2A = *reinterpret_cast<const f4*>(c2k + colb0);
    c2B = *reinterpret_cast<const f4*>(c2k + colb0 + 16);
    c2An = c2A; c2Bn = c2B;
  }
  WAITV(0);

  // prologue: stage steps 0 and 1 (4 VMEM each per wave)
  stageK8(Kn, KP[0],        KTLO+0, wid, l);
  stageK8(Kn, KP[0]+4096,   KTLO+1, wid, l);
  stageV8(Vn, VBs[0],       KTLO*16 + 0,  wid, l);
  stageK8(Kn, KP[1],        KTLO+2, wid, l);
  stageK8(Kn, KP[1]+4096,   KTLO+3, wid, l);
  stageV8(Vn, VBs[1],       KTLO*16 + 32, wid, l);

  const ffrag fz = {0.f,0.f,0.f,0.f};
  ffrag o[16];
  #pragma unroll
  for (int i=0;i<16;++i) o[i] = fz;
  float lsum = 0.f;                                  // per softmax-row q0w+lr, deferred reduce
  int q = q0w + lr;
  int s0l = lr + (lg&1)*32;                          // shfl source lane (low 4 cols)
  bool hi2 = (lg & 2) != 0;                          // tile-pair select
  int vswz = (lg ^ ((lr>>1)&3))<<3;                  // V read swizzle (u16 units)

  #pragma unroll
  for (int sp=0; sp<13; ++sp){
    if (sp < nsteps){
      if (sp == 0) { WAITV(4); }
      else if (sp < nsteps-1) { WAITV(6); }
      else { WAITV(0); }
      RBAR();
      const u16* kp = KP[sp&1];
      const u16* vb = VBs[sp&1];

      // QK^T for tile pair (2sp, 2sp+1): two independent MFMA chains
      __builtin_amdgcn_s_setprio(1);
      ffrag sA = fz, sB = fz;
      #pragma unroll
      for (int ks=0; ks<8; ++ks){
        int boff = (ks*64 + lg*16) ^ ((lr&7)<<4);
        bfrag kfA = ldb(kp + ((lr*512 + boff)>>1));
        bfrag kfB = ldb(kp + 4096 + ((lr*512 + boff)>>1));
        sA = MFMA16(kfA, qa[ks], sA);
        sB = MFMA16(kfB, qa[ks], sB);
      }
      __builtin_amdgcn_s_setprio(0);

      // P = exp(S + c2[col]) directly (logits bounded; row-const terms cancel),
      // masked via unsigned-range test; row-sum deferred to epilogue.
      int baseA = q + 132 - ((KTLO + 2*sp)*16 + lg*4);   // dA+132 for r=0
      #pragma unroll
      for (int r=0;r<4;++r){
        bool vA = (unsigned)(baseA - r)      < 265u;
        bool vB = (unsigned)(baseA - r - 16) < 265u;
        float eA = vA ? __expf(sA[r] + c2A[r]) : 0.f;
        float eB = vB ? __expf(sB[r] + c2B[r]) : 0.f;
        sA[r] = eA; sB[r] = eB; lsum += eA + eB;
      }

      // pack P via v_cvt_pk_bf16_f32 and rebuild PV A-frag via shfl (verified algebra)
      unsigned pk0A = cvtpk(sA[0], sA[1]);
      unsigned pk1A = cvtpk(sA[2], sA[3]);
      unsigned pk0B = cvtpk(sB[0], sB[1]);
      unsigned pk1B = cvtpk(sB[2], sB[3]);
      unsigned a0 = (unsigned)__shfl((int)pk0A, s0l,    64);
      unsigned a1 = (unsigned)__shfl((int)pk1A, s0l,    64);
      unsigned a2 = (unsigned)__shfl((int)pk0A, s0l+16, 64);
      unsigned a3 = (unsigned)__shfl((int)pk1A, s0l+16, 64);
      unsigned b0 = (unsigned)__shfl((int)pk0B, s0l,    64);
      unsigned b1 = (unsigned)__shfl((int)pk1B, s0l,    64);
      unsigned b2 = (unsigned)__shfl((int)pk0B, s0l+16, 64);
      unsigned b3 = (unsigned)__shfl((int)pk1B, s0l+16, 64);
      unsigned pu[4];
      pu[0] = hi2 ? b0 : a0;  pu[1] = hi2 ? b1 : a1;
      pu[2] = hi2 ? b2 : a2;  pu[3] = hi2 ? b3 : a3;
      bfrag pa; __builtin_memcpy(&pa, pu, 16);

      // PV: 16 independent accumulate chains over this 32-k chunk
      __builtin_amdgcn_s_setprio(1);
      #pragma unroll
      for (int ct=0; ct<16; ++ct){
        bfrag vf = ldb(vb + (ct*16 + lr)*32 + vswz);
        o[ct] = MFMA16(pa, vf, o[ct]);
      }
      __builtin_amdgcn_s_setprio(0);

      // preload c2 for next step BEFORE issuing next-next stage (keeps vmcnt counts exact)
      if (sp+1 < nsteps){
        int colbN = (KTLO + 2*(sp+1))*16 + lg*4;
        c2An = *reinterpret_cast<const f4*>(c2k + colbN);
        c2Bn = *reinterpret_cast<const f4*>(c2k + colbN + 16);
      }
      RBAR();
      if (sp+2 < nsteps){
        stageK8(Kn, KP[sp&1],      KTLO + 2*sp + 4, wid, l);
        stageK8(Kn, KP[sp&1]+4096, KTLO + 2*sp + 5, wid, l);
        stageV8(Vn, VBs[sp&1],     KTLO*16 + (sp+2)*32, wid, l);
      }
      c2A = c2An; c2B = c2Bn;
    }
  }

  // epilogue: single row-sum reduction, divide, folded BN, store
  lsum += __shfl_xor(lsum, 16, 64);
  lsum += __shfl_xor(lsum, 32, 64);
  float rinv = 1.f / lsum;                           // valid for row q0w+lr
  float linv[4];
  #pragma unroll
  for (int r=0;r<4;++r) linv[r] = __shfl(rinv, (lg<<2)+r, 64);  // row q0w+lg*4+r
  #pragma unroll
  for (int ct=0; ct<16; ++ct){
    int c = ct*16 + lr;
    float av = aV[c], bv = bV[c];
    #pragma unroll
    for (int r=0;r<4;++r)
      O[((size_t)(n*512 + q0w + lg*4 + r))*256 + c] = f2bf(av*(o[ct][r]*linv[r]) + bv);
  }
}

// ---------- W conv (round-9-proven): 128x128 tile + fused BN partials, direct stores ----------
__global__ __launch_bounds__(256, 2) void k_conv1(const u16* __restrict__ in1, const u16* __restrict__ in2,
    const u16* __restrict__ wp, const float* __restrict__ bias,
    u16* __restrict__ o1, u16* __restrict__ o2,
    float* __restrict__ psum, float* __restrict__ psq){
  __shared__ __align__(16) u16 As[2][8192];
  __shared__ __align__(16) u16 Bs[2][8192];
  int id = blockIdx.x;
  int xcd = id & 7, j = id >> 3;               // 256 per XCD
  int pl = j>>2, v = j&3;
  int ptile = xcd*64 + pl;
  int ot = v & 1, s = v >> 1;
  const u16* A = s ? in2 : in1;
  u16* out = s ? o2 : o1;

  int t = threadIdx.x, wid = t>>6, l = t&63, lr = l&15, lg = l>>4;
  int p0 = ptile*128, o0 = ot*128;
  int wr = (wid>>1)*64, wc = (wid&1)*64;
  int swz = (lr&7)<<4;

  stageT<4>(A, p0, 0,  As[0], wid, l);
  stageT<4>(wp, o0, 0, Bs[0], wid, l);
  stageT<4>(A, p0, 64, As[1], wid, l);
  stageT<4>(wp, o0, 64,Bs[1], wid, l);

  const ffrag fz = {0.f,0.f,0.f,0.f};
  ffrag acc[4][4];
  #pragma unroll
  for (int i=0;i<4;++i){ acc[i][0]=fz; acc[i][1]=fz; acc[i][2]=fz; acc[i][3]=fz; }

  #pragma unroll
  for (int ks=0; ks<4; ++ks){
    if (ks < 3) { WAITV(8); } else { WAITV(0); }
    RBAR();
    const u16* as = As[ks&1];
    const u16* bs = Bs[ks&1];
    #pragma unroll
    for (int kc=0; kc<2; ++kc){
      int colb = (kc*64 + lg*16) ^ swz;
      bfrag af[4], bfm[4];
      #pragma unroll
      for (int mt=0; mt<4; ++mt)
        af[mt] = ldb(as + (((wr + mt*16 + lr)*128 + colb)>>1));
      #pragma unroll
      for (int nt=0; nt<4; ++nt)
        bfm[nt] = ldb(bs + (((wc + nt*16 + lr)*128 + colb)>>1));
      #pragma unroll
      for (int mt=0; mt<4; ++mt)
        #pragma unroll
        for (int nt=0; nt<4; ++nt)
          acc[mt][nt] = MFMA16(af[mt], bfm[nt], acc[mt][nt]);
    }
    RBAR();
    if (ks < 2){
      stageT<4>(A, p0, (ks+2)*64, As[ks&1], wid, l);
      stageT<4>(wp, o0, (ks+2)*64, Bs[ks&1], wid, l);
    }
  }

  float pv[4], qv[4];
  #pragma unroll
  for (int nt=0; nt<4; ++nt){ pv[nt]=0.f; qv[nt]=0.f; }
  #pragma unroll
  for (int nt=0; nt<4; ++nt){
    int oo = o0 + wc + nt*16 + lr;
    float bsc = bias[oo];
    #pragma unroll
    for (int mt=0; mt<4; ++mt){
      int pr = p0 + wr + mt*16 + lg*4;
      #pragma unroll
      for (int rr=0;rr<4;++rr){
        float val = acc[mt][nt][rr] + bsc;
        out[(size_t)(pr + rr)*256 + oo] = f2bf(val);
        pv[nt] += val; qv[nt] += val*val;
      }
    }
  }
  #pragma unroll
  for (int nt=0; nt<4; ++nt){
    float sv = pv[nt], sq = qv[nt];
    sv += __shfl_xor(sv,16,64); sv += __shfl_xor(sv,32,64);
    sq += __shfl_xor(sq,16,64); sq += __shfl_xor(sq,32,64);
    if (lg==0){
      int oo = o0 + wc + nt*16 + lr;
      int idx = ((s*256 + oo)<<10) + (ptile<<1) + (wr>>6);
      psum[idx] = sv; psq[idx] = sq;
    }
  }
}

// ---------- u BN stats stage 2 (reduces conv1's fused partials, 1024 per channel) ----------
__global__ __launch_bounds__(256) void k_ustat2(const float* __restrict__ psum, const float* __restrict__ psq,
                                                const float* __restrict__ g, const float* __restrict__ be,
                                                float* __restrict__ aWall, float* __restrict__ bWall){
  int c = blockIdx.x, s = blockIdx.y, t = threadIdx.x;
  const float* ps = psum + (((size_t)s*256 + c)<<10);
  const float* pq = psq  + (((size_t)s*256 + c)<<10);
  float sm = ps[t] + ps[t+256] + ps[t+512] + ps[t+768];
  float sq = pq[t] + pq[t+256] + pq[t+512] + pq[t+768];
  __shared__ float rs[256], rq[256];
  rs[t]=sm; rq[t]=sq; __syncthreads();
  for (int st=128; st>0; st>>=1){ if (t<st){ rs[t]+=rs[t+st]; rq[t]+=rq[t+st]; } __syncthreads(); }
  if (t==0){
    float mean = rs[0]*(1.f/65536.f);
    float var  = rq[0]*(1.f/65536.f) - mean*mean;
    float aa = g[c]*rsqrtf(var + 1e-5f);
    aWall[s*256+c]=aa; bWall[s*256+c]=be[c]-aa*mean;
  }
}

// ---------- final: z = aW*u + bW + xr (bf16 residual), transpose back; float4 stores ----------
__global__ __launch_bounds__(256) void k_final(const u16* __restrict__ u1, const u16* __restrict__ u2,
                                               const u16* __restrict__ xr1, const u16* __restrict__ xr2,
                                               const float* __restrict__ aWall, const float* __restrict__ bWall,
                                               float* __restrict__ z){
  int s = blockIdx.z;
  const u16* u  = s ? u2 : u1;
  const u16* xr = s ? xr2 : xr1;
  const float* aW = aWall + s*256;
  const float* bW = bWall + s*256;
  float* zb = z + (size_t)s*16777216;
  __shared__ u16 Tu[64][66], Tx[64][66];
  int t = threadIdx.x;
  int p0 = blockIdx.x*64, c0 = blockIdx.y*64;
  int b = p0>>15, q0 = p0&32767;
  #pragma unroll
  for (int it=0; it<4; ++it){
    int pi = it*16 + (t>>4);
    int cj = (t&15)*4;
    u16x4 vu; __builtin_memcpy(&vu, u  + (size_t)(p0+pi)*256 + c0 + cj, 8);
    u16x4 vx; __builtin_memcpy(&vx, xr + (size_t)(p0+pi)*256 + c0 + cj, 8);
    *reinterpret_cast<u16x4*>(&Tu[pi][cj]) = vu;
    *reinterpret_cast<u16x4*>(&Tx[pi][cj]) = vx;
  }
  __syncthreads();
  int qi4 = (t&15)*4;
  #pragma unroll
  for (int it=0; it<4; ++it){
    int cc = it*16 + (t>>4);
    float a = aW[c0+cc], bw = bW[c0+cc];
    f4 vz;
    #pragma unroll
    for (int j=0;j<4;++j)
      vz[j] = a*bf2f(Tu[qi4+j][cc]) + bw + bf2f(Tx[qi4+j][cc]);
    *reinterpret_cast<f4*>(zb + ((size_t)(b*256 + c0 + cc))*32768 + q0 + qi4) = vz;
  }
}

extern "C" void kernel_launch(void* const* d_in, const int* in_sizes, int n_in,
                              void* d_out, int out_size, void* d_ws, size_t ws_size,
                              hipStream_t stream) {
  const float* x1  = (const float*)d_in[0];
  const float* x2  = (const float*)d_in[1];
  const float* Qw  = (const float*)d_in[2];
  const float* Qb  = (const float*)d_in[3];
  const float* Kw  = (const float*)d_in[4];
  const float* Kb  = (const float*)d_in[5];
  const float* Vw  = (const float*)d_in[6];
  const float* Vb  = (const float*)d_in[7];
  const float* Vg  = (const float*)d_in[8];
  const float* Vbe = (const float*)d_in[9];
  const float* Ww  = (const float*)d_in[10];
  const float* Wb  = (const float*)d_in[11];
  const float* Wg  = (const float*)d_in[12];
  const float* Wbe = (const float*)d_in[13];
  (void)Kb;                                   // folds into softmax row-constant (cancels)

  char* ws = (char*)d_ws;
  const size_t S = 33554432;                  // one (65536 x 256) bf16 slot = 32 MB
  u16* xr1 = (u16*)(ws + 0*S);                // stays live through k_final
  u16* xr2 = (u16*)(ws + 1*S);
  u16* XM1 = (u16*)(ws + 2*S);
  u16* u1  = (u16*)(ws + 3*S);
  u16* XM2 = (u16*)(ws + 4*S);
  u16* u2  = (u16*)(ws + 5*S);
  u16* wb  = (u16*)(ws + 6*S);                // 4 x 65536 bf16 = 512KB
  float* vec = (float*)(ws + 6*S + 524288);
  float* aVall = vec;                         // [2][256]
  float* bVall = vec + 512;
  float* aWall = vec + 1024;
  float* bWall = vec + 1536;
  u16*   wm    = (u16*)(vec + 10240);         // 256x256 bf16 = 128KB (M^T weight)
  float* g     = vec + 43008;                 // [256]
  float* c2all = vec + 43264;                 // [2][65536] fp32

  char* douts = (char*)d_out;                 // d_out = 128MB; scratch dead before z writes
  u16* Vt1 = (u16*)douts;                     // [0,32MB)   read by attn
  u16* Vt2 = (u16*)(douts + S);               // [32,64MB)
  u16* O1  = (u16*)(douts + 2*S);             // [64,96MB)  written by attn, read by conv1
  u16* O2  = (u16*)(douts + 3*S);             // [96,128MB)
  float* c2p   = (float*)douts;               // [0,2MB)  xpose partials, dead before qkv
  float* vpsum = (float*)(douts + 2*S);       // [64,68MB) qkv V partials, dead before attn O1
  float* vpsq  = vpsum + 1048576;             // [68,72MB)
  float* upsum = (float*)douts;               // [0,2MB)  reused again after attn
  float* upsq  = upsum + 524288;              // [2,4MB)
  float* z = (float*)d_out;

  dim3 gt(1024, 4, 2);
  dim3 gcr(256, 2);
  dim3 gv2(256, 2);
  dim3 gu2(256, 2);

  k_wcvt<<<256, 256, 0, stream>>>(Qw, Kw, Vw, Ww, wb);
  k_g<<<1, 256, 0, stream>>>(Qb, Kw, g);
  k_mg<<<256, 256, 0, stream>>>(wb, wm);
  k_xpose<<<gt, 256, 0, stream>>>(x1, x2, xr1, xr2, g, c2p);
  k_c2red<<<gcr, 256, 0, stream>>>(c2p, c2all);
  k_qkv<<<8192, 256, 0, stream>>>(xr1, xr2, wb, wm, Vb, XM1, Vt1, XM2, Vt2, vpsum, vpsq);
  k_vstat2<<<gv2, 256, 0, stream>>>(vpsum, vpsq, Vg, Vbe, aVall, bVall);
  k_attn<<<1024, 512, 0, stream>>>(XM1, xr2, Vt2, XM2, xr1, Vt1, aVall, bVall, c2all, O1, O2);
  k_conv1<<<2048, 256, 0, stream>>>(O1, O2, wb + 196608, Wb, u1, u2, upsum, upsq);
  k_ustat2<<<gu2, 256, 0, stream>>>(upsum, upsq, Wg, Wbe, aWall, bWall);
  k_final<<<gt, 256, 0, stream>>>(u1, u2, xr1, xr2, aWall, bWall, z);
}

// Round 19
// 330.486 us; speedup vs baseline: 1.0678x; 1.0678x over previous
//
#include <hip/hip_runtime.h>

typedef unsigned short u16;
typedef short bfrag __attribute__((ext_vector_type(8)));   // 8 bf16 = one K=32 MFMA A/B frag
typedef float ffrag __attribute__((ext_vector_type(4)));   // MFMA C/D frag
typedef u16 u16x4 __attribute__((ext_vector_type(4)));
typedef float f4 __attribute__((ext_vector_type(4)));

#define MFMA16(a,b,c)  __builtin_amdgcn_mfma_f32_16x16x32_bf16((a),(b),(c),0,0,0)

#define WAITV(N) do { asm volatile("s_waitcnt vmcnt(" #N ")" ::: "memory"); \
                      __builtin_amdgcn_sched_barrier(0); } while(0)
#define RBAR()   do { __builtin_amdgcn_s_barrier(); \
                      __builtin_amdgcn_sched_barrier(0); } while(0)

// B=2, C=256, H=64, W=512 ; PIX=65536 ; NROW=B*H=128 ; max_w=int(512*0.26)=133 -> |i-j|<=132
// QK-fold: S = x1·M·x2^T + c2[p'] (+row-const terms that cancel in softmax),
//          M[c,d] = sum_o Qw[o,c]Kw[o,d], g[d] = sum_o Qb[o]Kw[o,d], c2 = x_k-side · g.

__device__ __forceinline__ u16 f2bf(float f){
  union { float f; unsigned int i; } cv; cv.f = f;
  unsigned int x = cv.i;
  return (u16)((x + 0x7fffu + ((x >> 16) & 1u)) >> 16);  // RNE
}
__device__ __forceinline__ float bf2f(u16 u){
  union { unsigned int i; float f; } cv;
  cv.i = ((unsigned int)u) << 16;
  return cv.f;
}
__device__ __forceinline__ unsigned cvtpk(float lo, float hi){
  unsigned r; asm("v_cvt_pk_bf16_f32 %0, %1, %2" : "=v"(r) : "v"(lo), "v"(hi)); return r;
}
__device__ __forceinline__ bfrag ldb(const u16* p){
  bfrag v; __builtin_memcpy(&v, p, 16); return v;
}
__device__ __forceinline__ void gload_lds16(const u16* g, u16* l){
  __builtin_amdgcn_global_load_lds(
      (const __attribute__((address_space(1))) unsigned int*)g,
      (__attribute__((address_space(3))) unsigned int*)l, 16, 0, 0);
}

// ---------- weights fp32 -> bf16 ----------
__global__ __launch_bounds__(256) void k_wcvt(const float* __restrict__ qw, const float* __restrict__ kw,
                                              const float* __restrict__ vw, const float* __restrict__ ww,
                                              u16* __restrict__ out){
  int t = blockIdx.x*256 + threadIdx.x;
  out[t]        = f2bf(qw[t]);
  out[t+65536]  = f2bf(kw[t]);
  out[t+131072] = f2bf(vw[t]);
  out[t+196608] = f2bf(ww[t]);
}

// ---------- g[d] = sum_o Qb[o]*Kw[o,d] (fp32 sources) ----------
__global__ __launch_bounds__(256) void k_g(const float* __restrict__ Qb, const float* __restrict__ Kw,
                                           float* __restrict__ g){
  int t = threadIdx.x;
  float sm = 0.f;
  #pragma unroll 8
  for (int o=0;o<256;++o) sm += Qb[o]*Kw[o*256 + t];
  g[t] = sm;
}

// ---------- wm[d*256+c] = M[c,d] = sum_o Qw[o,c]*Kw[o,d] ----------
__global__ __launch_bounds__(256) void k_mg(const u16* __restrict__ wb, u16* __restrict__ wm){
  int c = blockIdx.x, t = threadIdx.x;
  float sm = 0.f;
  #pragma unroll 8
  for (int o=0;o<256;++o) sm += bf2f(wb[o*256 + c]) * bf2f(wb[65536 + o*256 + t]);
  wm[t*256 + c] = f2bf(sm);
}

// ---------- x (B,C,H,W) fp32 -> xr (p, c) bf16 ; fused c2 partials (x·g) ----------
__global__ __launch_bounds__(256) void k_xpose(const float* __restrict__ x1, const float* __restrict__ x2,
                                               u16* __restrict__ xr1, u16* __restrict__ xr2,
                                               const float* __restrict__ g, float* __restrict__ c2p){
  const float* x = blockIdx.z ? x2 : x1;
  u16* xr = blockIdx.z ? xr2 : xr1;
  __shared__ float T[64][65];
  __shared__ float c2l[4][64];
  int t = threadIdx.x;
  int p0 = blockIdx.x*64, c0 = blockIdx.y*64;
  int b = p0 >> 15, q0 = p0 & 32767;
  float part0=0.f, part1=0.f, part2=0.f, part3=0.f;
  #pragma unroll
  for (int it=0; it<4; ++it){
    int cc = it*16 + (t>>4);
    int pi = (t&15)*4;
    ffrag v; __builtin_memcpy(&v, x + ((size_t)(b*256 + c0 + cc))*32768 + q0 + pi, 16);
    T[cc][pi+0]=v[0]; T[cc][pi+1]=v[1]; T[cc][pi+2]=v[2]; T[cc][pi+3]=v[3];
    float gc = g[c0 + cc];
    part0 += v[0]*gc; part1 += v[1]*gc; part2 += v[2]*gc; part3 += v[3]*gc;
  }
  part0 += __shfl_xor(part0,16,64); part0 += __shfl_xor(part0,32,64);
  part1 += __shfl_xor(part1,16,64); part1 += __shfl_xor(part1,32,64);
  part2 += __shfl_xor(part2,16,64); part2 += __shfl_xor(part2,32,64);
  part3 += __shfl_xor(part3,16,64); part3 += __shfl_xor(part3,32,64);
  int w = t>>6, lane = t&63;
  if (lane < 16){
    c2l[w][lane*4+0]=part0; c2l[w][lane*4+1]=part1;
    c2l[w][lane*4+2]=part2; c2l[w][lane*4+3]=part3;
  }
  __syncthreads();
  int pi = t>>2, cj0 = (t&3)*16;
  u16 tmp[16];
  #pragma unroll
  for (int j=0;j<16;++j) tmp[j] = f2bf(T[cj0+j][pi]);
  __builtin_memcpy(xr + (size_t)(p0+pi)*256 + c0 + cj0, tmp, 32);
  if (t < 64){
    float smm = c2l[0][t] + c2l[1][t] + c2l[2][t] + c2l[3][t];
    c2p[(((size_t)blockIdx.y*2 + blockIdx.z)<<16) + p0 + t] = smm;
  }
}

// ---------- reduce 4 c2 quarters -> c2all[s][p] ----------
__global__ __launch_bounds__(256) void k_c2red(const float* __restrict__ c2p, float* __restrict__ c2all){
  int s = blockIdx.y;
  int row = blockIdx.x*256 + threadIdx.x;
  float smm = c2p[((size_t)(0*2+s)<<16) + row] + c2p[((size_t)(1*2+s)<<16) + row]
            + c2p[((size_t)(2*2+s)<<16) + row] + c2p[((size_t)(3*2+s)<<16) + row];
  c2all[s*65536 + row] = smm;
}

// ---------- tile staging: NI*4KB, rows of 128B (64 k-cols bf16), XOR-swizzled ----------
template<int NI>
__device__ __forceinline__ void stageT(const u16* __restrict__ src, int row0, int k0,
                                       u16* lds, int wid, int l){
  #pragma unroll
  for (int rr=0; rr<NI; ++rr){
    int off = rr*4096 + wid*1024 + l*16;        // byte offset in tile
    int row = off>>7, inb = off&127;
    int srcb = inb ^ ((row&7)<<4);              // pre-swizzled source (rule 21)
    gload_lds16(src + (size_t)(row0+row)*256 + k0 + (srcb>>1),
                lds + ((rr*4096 + wid*1024)>>1));
  }
}

// ---------- fused XM/V conv: 128p x 64o tiles, BK=64, 3 blk/CU; V-BN partials fused ----------
__global__ __launch_bounds__(256, 3) void k_qkv(const u16* __restrict__ xr1, const u16* __restrict__ xr2,
    const u16* __restrict__ wb, const u16* __restrict__ wm,
    const float* __restrict__ vb,
    u16* __restrict__ XM1, u16* __restrict__ V1,
    u16* __restrict__ XM2, u16* __restrict__ V2,
    float* __restrict__ vpsum, float* __restrict__ vpsq){
  __shared__ __align__(16) u16 As[2][8192];     // 2 x 16KB (128 rows)
  __shared__ __align__(16) u16 Bs[2][4096];     // 2 x 8KB  (64 rows)
  int id = blockIdx.x;
  int xcd = id & 7, j = id >> 3;                // 1024 per XCD
  int pl = j >> 4, v = j & 15;                  // 64 p-tiles x 16 variants per XCD
  int ptile = xcd*64 + pl;
  int ot = v & 3, r = v >> 2;
  int wgtV = r >> 1, s = r & 1;                 // wgtV: 0=XM, 1=V
  const u16* A = s ? xr2 : xr1;
  const u16* W = wgtV ? (wb + 131072) : wm;

  int t = threadIdx.x, wid = t>>6, l = t&63, lr = l&15, lg = l>>4;
  int p0 = ptile*128, o0 = ot*64;
  int wr = wid*32;
  int swz = (lr&7)<<4;

  stageT<4>(A, p0, 0,  As[0], wid, l);
  stageT<2>(W, o0, 0,  Bs[0], wid, l);
  stageT<4>(A, p0, 64, As[1], wid, l);
  stageT<2>(W, o0, 64, Bs[1], wid, l);

  const ffrag fz = {0.f,0.f,0.f,0.f};
  ffrag acc[2][4];
  #pragma unroll
  for (int i=0;i<2;++i){ acc[i][0]=fz; acc[i][1]=fz; acc[i][2]=fz; acc[i][3]=fz; }

  #pragma unroll
  for (int ks=0; ks<4; ++ks){
    if (ks < 3) { WAITV(6); } else { WAITV(0); }
    RBAR();
    const u16* as = As[ks&1];
    const u16* bs = Bs[ks&1];
    #pragma unroll
    for (int kc=0; kc<2; ++kc){
      int colb = (kc*64 + lg*16) ^ swz;
      bfrag af[2], bf[4];
      #pragma unroll
      for (int mt=0; mt<2; ++mt)
        af[mt] = ldb(as + (((wr + mt*16 + lr)*128 + colb)>>1));
      #pragma unroll
      for (int nt=0; nt<4; ++nt)
        bf[nt] = ldb(bs + (((nt*16 + lr)*128 + colb)>>1));
      if (!wgtV){
        #pragma unroll
        for (int mt=0; mt<2; ++mt)
          #pragma unroll
          for (int nt=0; nt<4; ++nt)
            acc[mt][nt] = MFMA16(bf[nt], af[mt], acc[mt][nt]);   // D[o][p] (swapped)
      } else {
        #pragma unroll
        for (int mt=0; mt<2; ++mt)
          #pragma unroll
          for (int nt=0; nt<4; ++nt)
            acc[mt][nt] = MFMA16(af[mt], bf[nt], acc[mt][nt]);   // D[p][o]
      }
    }
    RBAR();
    if (ks < 2){
      stageT<4>(A, p0, (ks+2)*64, As[ks&1], wid, l);
      stageT<2>(W, o0, (ks+2)*64, Bs[ks&1], wid, l);
    }
  }

  if (!wgtV){
    u16* op = s ? XM2 : XM1;                    // no bias (row-terms cancel in softmax)
    #pragma unroll
    for (int nt=0; nt<4; ++nt){
      int ob = o0 + nt*16 + lg*4;
      #pragma unroll
      for (int mt=0; mt<2; ++mt){
        int p = p0 + wr + mt*16 + lr;
        u16x4 vv;
        #pragma unroll
        for (int rr=0;rr<4;++rr) vv[rr] = f2bf(acc[mt][nt][rr]);
        *reinterpret_cast<u16x4*>(op + (size_t)p*256 + ob) = vv;
      }
    }
  } else {
    u16* Vt = s ? V2 : V1;
    float pvv[4], qvv[4];
    #pragma unroll
    for (int nt=0; nt<4; ++nt){ pvv[nt]=0.f; qvv[nt]=0.f; }
    #pragma unroll
    for (int nt=0; nt<4; ++nt){
      int oo = o0 + nt*16 + lr;
      float bsc = vb[oo];
      #pragma unroll
      for (int mt=0; mt<2; ++mt){
        int pr = p0 + wr + mt*16 + lg*4;
        int n = pr >> 9, w0 = pr & 511;
        u16x4 vv;
        #pragma unroll
        for (int rr=0;rr<4;++rr){
          float val = acc[mt][nt][rr] + bsc;
          vv[rr] = f2bf(val);
          pvv[nt] += val; qvv[nt] += val*val;
        }
        *reinterpret_cast<u16x4*>(Vt + ((size_t)(n*256 + oo))*512 + w0) = vv;
      }
    }
    #pragma unroll
    for (int nt=0; nt<4; ++nt){
      float sv = pvv[nt], sq = qvv[nt];
      sv += __shfl_xor(sv,16,64); sv += __shfl_xor(sv,32,64);
      sq += __shfl_xor(sq,16,64); sq += __shfl_xor(sq,32,64);
      if (lg==0){
        int oo = o0 + nt*16 + lr;
        size_t idx = (((size_t)(s*256 + oo))<<11) + (ptile<<2) + wid;
        vpsum[idx] = sv; vpsq[idx] = sq;
      }
    }
  }
}

// ---------- V BN stats stage 2 (reduces qkv's fused partials, 2048 per channel) ----------
__global__ __launch_bounds__(256) void k_vstat2(const float* __restrict__ ps, const float* __restrict__ pq,
                                                const float* __restrict__ g, const float* __restrict__ be,
                                                float* __restrict__ aVall, float* __restrict__ bVall){
  int c = blockIdx.x, s = blockIdx.y, t = threadIdx.x;
  const float* psb = ps + (((size_t)(s*256 + c))<<11);
  const float* pqb = pq + (((size_t)(s*256 + c))<<11);
  float sm=0.f, sq=0.f;
  #pragma unroll
  for (int j2=0;j2<8;++j2){ sm += psb[t + j2*256]; sq += pqb[t + j2*256]; }
  __shared__ float rs[256], rq[256];
  rs[t]=sm; rq[t]=sq; __syncthreads();
  for (int st=128; st>0; st>>=1){ if (t<st){ rs[t]+=rs[t+st]; rq[t]+=rq[t+st]; } __syncthreads(); }
  if (t==0){
    float mean = rs[0]*(1.f/65536.f);
    float var  = rq[0]*(1.f/65536.f) - mean*mean;
    float aa = g[c]*rsqrtf(var + 1e-5f);
    aVall[s*256+c]=aa; bVall[s*256+c]=be[c]-aa*mean;
  }
}

// ---------- staging helpers for k_attn ----------
__device__ __forceinline__ void stageK(const u16* Kn, u16* kb, int kt, int wid, int l){
  #pragma unroll
  for (int c2=0; c2<2; ++c2){
    int off = wid*2048 + c2*1024 + l*16;            // byte offset in 8KB tile
    int row = off>>9, inb = off&511;
    int src = inb ^ ((row&7)<<4);                   // pre-swizzled source
    gload_lds16(Kn + (size_t)(kt*16+row)*256 + (src>>1), kb + wid*1024 + c2*512);
  }
}
// V tile 16KB: channel c holds its 32-k chunk at byte c*64; 16B slot swizzled by (c>>1)&3
__device__ __forceinline__ void stageV(const u16* Vn, u16* vb, int k0, int wid, int l){
  #pragma unroll
  for (int c4=0; c4<4; ++c4){
    int off = wid*4096 + c4*1024 + l*16;            // byte offset in 16KB tile
    int crow = off>>6, slot = (off>>4)&3;
    int kk = slot ^ ((crow>>1)&3);                  // pre-swizzled source chunk
    gload_lds16(Vn + (size_t)crow*512 + k0 + (kk<<3), vb + ((wid*4096 + c4*1024)>>1));
  }
}

// ---------- banded attention v7+prio: flash loop, QK-fold (K = raw xr, +c2[col]) ----------
__global__ __launch_bounds__(256, 2) void k_attn(
    const u16* __restrict__ XM1, const u16* __restrict__ xr2, const u16* __restrict__ V2,
    const u16* __restrict__ XM2, const u16* __restrict__ xr1, const u16* __restrict__ V1,
    const float* __restrict__ aVall, const float* __restrict__ bVall,
    const float* __restrict__ c2all,
    u16* __restrict__ O1, u16* __restrict__ O2){
  __shared__ __align__(16) u16 KP[2][8192];          // 2 x 16KB: K tile-pair dbuf
  __shared__ __align__(16) u16 VBs[2][8192];         // 2 x 16KB: V chunk dbuf
  int t = threadIdx.x, wid = t>>6, l = t&63, lr = l&15, lg = l>>4;
  int id = blockIdx.x;
  int s = id >> 10;
  int r0 = id & 1023;
  int xcd = r0 & 7, s5 = r0 >> 3;
  int qb = s5 & 7, n = (xcd<<4) | (s5>>3);
  const u16* Q = s ? XM2 : XM1;
  const u16* K = s ? xr1 : xr2;
  const u16* V = s ? V1 : V2;
  const float* aV = aVall + (s ? 0 : 256);
  const float* bV = bVall + (s ? 0 : 256);
  const float* c2k = c2all + ((s^1)<<16) + n*512;    // c2 of the K-side stream
  u16* O = s ? O2 : O1;

  int q0 = qb*64, q0w = q0 + wid*16;
  int lo = q0 - 132; if (lo < 0) lo = 0;
  int hi = q0 + 195; if (hi > 511) hi = 511;
  int KTLO = (lo>>4) & ~1;                           // even
  int KTHI = (hi>>4) | 1;                            // odd
  int nsteps = (KTHI - KTLO + 2) >> 1;               // 7..12 steps of 32 k-cols

  const u16* Kn = K + (size_t)n*131072;
  const u16* Vn = V + (size_t)n*131072;

  // Q frags + step-0 c2; drain so vmcnt literals below are exact
  bfrag qa[8];
  const u16* Qrow = Q + ((size_t)(n*512 + q0w + lr))*256 + lg*8;
  #pragma unroll
  for (int ks=0; ks<8; ++ks) qa[ks] = ldb(Qrow + ks*32);
  f4 c2A, c2B, c2An, c2Bn;
  {
    int colb0 = KTLO*16 + lg*4;
    c2A = *reinterpret_cast<const f4*>(c2k + colb0);
    c2B = *reinterpret_cast<const f4*>(c2k + colb0 + 16);
    c2An = c2A; c2Bn = c2B;
  }
  WAITV(0);

  // prologue: stage steps 0 and 1 (8 VMEM each per wave)
  stageK(Kn, KP[0],        KTLO+0, wid, l);
  stageK(Kn, KP[0]+4096,   KTLO+1, wid, l);
  stageV(Vn, VBs[0],       KTLO*16 + 0,  wid, l);
  stageK(Kn, KP[1],        KTLO+2, wid, l);
  stageK(Kn, KP[1]+4096,   KTLO+3, wid, l);
  stageV(Vn, VBs[1],       KTLO*16 + 32, wid, l);

  const ffrag fz = {0.f,0.f,0.f,0.f};
  ffrag o[16];
  #pragma unroll
  for (int i=0;i<16;++i) o[i] = fz;
  float lsum = 0.f;                                  // per softmax-row q0w+lr, deferred reduce
  int q = q0w + lr;
  int s0l = lr + (lg&1)*32;                          // shfl source lane (low 4 cols)
  bool hi2 = (lg & 2) != 0;                          // tile-pair select
  int vswz = (lg ^ ((lr>>1)&3))<<3;                  // V read swizzle (u16 units)

  #pragma unroll
  for (int sp=0; sp<12; ++sp){
    if (sp < nsteps){
      if (sp == 0) { WAITV(8); }
      else if (sp < nsteps-1) { WAITV(10); }
      else { WAITV(0); }
      RBAR();
      const u16* kp = KP[sp&1];
      const u16* vb = VBs[sp&1];

      // QK^T for tile pair (2sp, 2sp+1): two independent MFMA chains
      __builtin_amdgcn_s_setprio(1);
      ffrag sA = fz, sB = fz;
      #pragma unroll
      for (int ks=0; ks<8; ++ks){
        int boff = (ks*64 + lg*16) ^ ((lr&7)<<4);
        bfrag kfA = ldb(kp + ((lr*512 + boff)>>1));
        bfrag kfB = ldb(kp + 4096 + ((lr*512 + boff)>>1));
        sA = MFMA16(kfA, qa[ks], sA);
        sB = MFMA16(kfB, qa[ks], sB);
      }
      __builtin_amdgcn_s_setprio(0);

      // P = exp(S + c2[col]) directly (logits bounded; row-const terms cancel),
      // masked via unsigned-range test; row-sum deferred to epilogue.
      int baseA = q + 132 - ((KTLO + 2*sp)*16 + lg*4);   // dA+132 for r=0
      #pragma unroll
      for (int r=0;r<4;++r){
        bool vA = (unsigned)(baseA - r)      < 265u;
        bool vB = (unsigned)(baseA - r - 16) < 265u;
        float eA = vA ? __expf(sA[r] + c2A[r]) : 0.f;
        float eB = vB ? __expf(sB[r] + c2B[r]) : 0.f;
        sA[r] = eA; sB[r] = eB; lsum += eA + eB;
      }

      // pack P via v_cvt_pk_bf16_f32 and rebuild PV A-frag via shfl (verified algebra)
      unsigned pk0A = cvtpk(sA[0], sA[1]);
      unsigned pk1A = cvtpk(sA[2], sA[3]);
      unsigned pk0B = cvtpk(sB[0], sB[1]);
      unsigned pk1B = cvtpk(sB[2], sB[3]);
      unsigned a0 = (unsigned)__shfl((int)pk0A, s0l,    64);
      unsigned a1 = (unsigned)__shfl((int)pk1A, s0l,    64);
      unsigned a2 = (unsigned)__shfl((int)pk0A, s0l+16, 64);
      unsigned a3 = (unsigned)__shfl((int)pk1A, s0l+16, 64);
      unsigned b0 = (unsigned)__shfl((int)pk0B, s0l,    64);
      unsigned b1 = (unsigned)__shfl((int)pk1B, s0l,    64);
      unsigned b2 = (unsigned)__shfl((int)pk0B, s0l+16, 64);
      unsigned b3 = (unsigned)__shfl((int)pk1B, s0l+16, 64);
      unsigned pu[4];
      pu[0] = hi2 ? b0 : a0;  pu[1] = hi2 ? b1 : a1;
      pu[2] = hi2 ? b2 : a2;  pu[3] = hi2 ? b3 : a3;
      bfrag pa; __builtin_memcpy(&pa, pu, 16);

      // PV: 16 independent accumulate chains over this 32-k chunk
      __builtin_amdgcn_s_setprio(1);
      #pragma unroll
      for (int ct=0; ct<16; ++ct){
        bfrag vf = ldb(vb + (ct*16 + lr)*32 + vswz);
        o[ct] = MFMA16(pa, vf, o[ct]);
      }
      __builtin_amdgcn_s_setprio(0);

      // preload c2 for next step BEFORE issuing next-next stage (keeps vmcnt counts exact)
      if (sp+1 < nsteps){
        int colbN = (KTLO + 2*(sp+1))*16 + lg*4;
        c2An = *reinterpret_cast<const f4*>(c2k + colbN);
        c2Bn = *reinterpret_cast<const f4*>(c2k + colbN + 16);
      }
      RBAR();
      if (sp+2 < nsteps){
        stageK(Kn, KP[sp&1],      KTLO + 2*sp + 4, wid, l);
        stageK(Kn, KP[sp&1]+4096, KTLO + 2*sp + 5, wid, l);
        stageV(Vn, VBs[sp&1],     KTLO*16 + (sp+2)*32, wid, l);
      }
      c2A = c2An; c2B = c2Bn;
    }
  }

  // epilogue: single row-sum reduction, divide, folded BN, store
  lsum += __shfl_xor(lsum, 16, 64);
  lsum += __shfl_xor(lsum, 32, 64);
  float rinv = 1.f / lsum;                           // valid for row q0w+lr
  float linv[4];
  #pragma unroll
  for (int r=0;r<4;++r) linv[r] = __shfl(rinv, (lg<<2)+r, 64);  // row q0w+lg*4+r
  #pragma unroll
  for (int ct=0; ct<16; ++ct){
    int c = ct*16 + lr;
    float av = aV[c], bv = bV[c];
    #pragma unroll
    for (int r=0;r<4;++r)
      O[((size_t)(n*512 + q0w + lg*4 + r))*256 + c] = f2bf(av*(o[ct][r]*linv[r]) + bv);
  }
}

// ---------- W conv (round-9-proven): 128x128 tile + fused BN partials, direct stores ----------
__global__ __launch_bounds__(256, 2) void k_conv1(const u16* __restrict__ in1, const u16* __restrict__ in2,
    const u16* __restrict__ wp, const float* __restrict__ bias,
    u16* __restrict__ o1, u16* __restrict__ o2,
    float* __restrict__ psum, float* __restrict__ psq){
  __shared__ __align__(16) u16 As[2][8192];
  __shared__ __align__(16) u16 Bs[2][8192];
  int id = blockIdx.x;
  int xcd = id & 7, j = id >> 3;               // 256 per XCD
  int pl = j>>2, v = j&3;
  int ptile = xcd*64 + pl;
  int ot = v & 1, s = v >> 1;
  const u16* A = s ? in2 : in1;
  u16* out = s ? o2 : o1;

  int t = threadIdx.x, wid = t>>6, l = t&63, lr = l&15, lg = l>>4;
  int p0 = ptile*128, o0 = ot*128;
  int wr = (wid>>1)*64, wc = (wid&1)*64;
  int swz = (lr&7)<<4;

  stageT<4>(A, p0, 0,  As[0], wid, l);
  stageT<4>(wp, o0, 0, Bs[0], wid, l);
  stageT<4>(A, p0, 64, As[1], wid, l);
  stageT<4>(wp, o0, 64,Bs[1], wid, l);

  const ffrag fz = {0.f,0.f,0.f,0.f};
  ffrag acc[4][4];
  #pragma unroll
  for (int i=0;i<4;++i){ acc[i][0]=fz; acc[i][1]=fz; acc[i][2]=fz; acc[i][3]=fz; }

  #pragma unroll
  for (int ks=0; ks<4; ++ks){
    if (ks < 3) { WAITV(8); } else { WAITV(0); }
    RBAR();
    const u16* as = As[ks&1];
    const u16* bs = Bs[ks&1];
    #pragma unroll
    for (int kc=0; kc<2; ++kc){
      int colb = (kc*64 + lg*16) ^ swz;
      bfrag af[4], bfm[4];
      #pragma unroll
      for (int mt=0; mt<4; ++mt)
        af[mt] = ldb(as + (((wr + mt*16 + lr)*128 + colb)>>1));
      #pragma unroll
      for (int nt=0; nt<4; ++nt)
        bfm[nt] = ldb(bs + (((wc + nt*16 + lr)*128 + colb)>>1));
      #pragma unroll
      for (int mt=0; mt<4; ++mt)
        #pragma unroll
        for (int nt=0; nt<4; ++nt)
          acc[mt][nt] = MFMA16(af[mt], bfm[nt], acc[mt][nt]);
    }
    RBAR();
    if (ks < 2){
      stageT<4>(A, p0, (ks+2)*64, As[ks&1], wid, l);
      stageT<4>(wp, o0, (ks+2)*64, Bs[ks&1], wid, l);
    }
  }

  float pv[4], qv[4];
  #pragma unroll
  for (int nt=0; nt<4; ++nt){ pv[nt]=0.f; qv[nt]=0.f; }
  #pragma unroll
  for (int nt=0; nt<4; ++nt){
    int oo = o0 + wc + nt*16 + lr;
    float bsc = bias[oo];
    #pragma unroll
    for (int mt=0; mt<4; ++mt){
      int pr = p0 + wr + mt*16 + lg*4;
      #pragma unroll
      for (int rr=0;rr<4;++rr){
        float val = acc[mt][nt][rr] + bsc;
        out[(size_t)(pr + rr)*256 + oo] = f2bf(val);
        pv[nt] += val; qv[nt] += val*val;
      }
    }
  }
  #pragma unroll
  for (int nt=0; nt<4; ++nt){
    float sv = pv[nt], sq = qv[nt];
    sv += __shfl_xor(sv,16,64); sv += __shfl_xor(sv,32,64);
    sq += __shfl_xor(sq,16,64); sq += __shfl_xor(sq,32,64);
    if (lg==0){
      int oo = o0 + wc + nt*16 + lr;
      int idx = ((s*256 + oo)<<10) + (ptile<<1) + (wr>>6);
      psum[idx] = sv; psq[idx] = sq;
    }
  }
}

// ---------- u BN stats stage 2 (reduces conv1's fused partials, 1024 per channel) ----------
__global__ __launch_bounds__(256) void k_ustat2(const float* __restrict__ psum, const float* __restrict__ psq,
                                                const float* __restrict__ g, const float* __restrict__ be,
                                                float* __restrict__ aWall, float* __restrict__ bWall){
  int c = blockIdx.x, s = blockIdx.y, t = threadIdx.x;
  const float* ps = psum + (((size_t)s*256 + c)<<10);
  const float* pq = psq  + (((size_t)s*256 + c)<<10);
  float sm = ps[t] + ps[t+256] + ps[t+512] + ps[t+768];
  float sq = pq[t] + pq[t+256] + pq[t+512] + pq[t+768];
  __shared__ float rs[256], rq[256];
  rs[t]=sm; rq[t]=sq; __syncthreads();
  for (int st=128; st>0; st>>=1){ if (t<st){ rs[t]+=rs[t+st]; rq[t]+=rq[t+st]; } __syncthreads(); }
  if (t==0){
    float mean = rs[0]*(1.f/65536.f);
    float var  = rq[0]*(1.f/65536.f) - mean*mean;
    float aa = g[c]*rsqrtf(var + 1e-5f);
    aWall[s*256+c]=aa; bWall[s*256+c]=be[c]-aa*mean;
  }
}

// ---------- final: z = aW*u + bW + xr (bf16 residual), transpose back; float4 stores ----------
__global__ __launch_bounds__(256) void k_final(const u16* __restrict__ u1, const u16* __restrict__ u2,
                                               const u16* __restrict__ xr1, const u16* __restrict__ xr2,
                                               const float* __restrict__ aWall, const float* __restrict__ bWall,
                                               float* __restrict__ z){
  int s = blockIdx.z;
  const u16* u  = s ? u2 : u1;
  const u16* xr = s ? xr2 : xr1;
  const float* aW = aWall + s*256;
  const float* bW = bWall + s*256;
  float* zb = z + (size_t)s*16777216;
  __shared__ u16 Tu[64][66], Tx[64][66];
  int t = threadIdx.x;
  int p0 = blockIdx.x*64, c0 = blockIdx.y*64;
  int b = p0>>15, q0 = p0&32767;
  #pragma unroll
  for (int it=0; it<4; ++it){
    int pi = it*16 + (t>>4);
    int cj = (t&15)*4;
    u16x4 vu; __builtin_memcpy(&vu, u  + (size_t)(p0+pi)*256 + c0 + cj, 8);
    u16x4 vx; __builtin_memcpy(&vx, xr + (size_t)(p0+pi)*256 + c0 + cj, 8);
    *reinterpret_cast<u16x4*>(&Tu[pi][cj]) = vu;
    *reinterpret_cast<u16x4*>(&Tx[pi][cj]) = vx;
  }
  __syncthreads();
  int qi4 = (t&15)*4;
  #pragma unroll
  for (int it=0; it<4; ++it){
    int cc = it*16 + (t>>4);
    float a = aW[c0+cc], bw = bW[c0+cc];
    f4 vz;
    #pragma unroll
    for (int j=0;j<4;++j)
      vz[j] = a*bf2f(Tu[qi4+j][cc]) + bw + bf2f(Tx[qi4+j][cc]);
    *reinterpret_cast<f4*>(zb + ((size_t)(b*256 + c0 + cc))*32768 + q0 + qi4) = vz;
  }
}

extern "C" void kernel_launch(void* const* d_in, const int* in_sizes, int n_in,
                              void* d_out, int out_size, void* d_ws, size_t ws_size,
                              hipStream_t stream) {
  const float* x1  = (const float*)d_in[0];
  const float* x2  = (const float*)d_in[1];
  const float* Qw  = (const float*)d_in[2];
  const float* Qb  = (const float*)d_in[3];
  const float* Kw  = (const float*)d_in[4];
  const float* Kb  = (const float*)d_in[5];
  const float* Vw  = (const float*)d_in[6];
  const float* Vb  = (const float*)d_in[7];
  const float* Vg  = (const float*)d_in[8];
  const float* Vbe = (const float*)d_in[9];
  const float* Ww  = (const float*)d_in[10];
  const float* Wb  = (const float*)d_in[11];
  const float* Wg  = (const float*)d_in[12];
  const float* Wbe = (const float*)d_in[13];
  (void)Kb;                                   // folds into softmax row-constant (cancels)

  char* ws = (char*)d_ws;
  const size_t S = 33554432;                  // one (65536 x 256) bf16 slot = 32 MB
  u16* xr1 = (u16*)(ws + 0*S);                // stays live through k_final
  u16* xr2 = (u16*)(ws + 1*S);
  u16* XM1 = (u16*)(ws + 2*S);
  u16* u1  = (u16*)(ws + 3*S);
  u16* XM2 = (u16*)(ws + 4*S);
  u16* u2  = (u16*)(ws + 5*S);
  u16* wb  = (u16*)(ws + 6*S);                // 4 x 65536 bf16 = 512KB
  float* vec = (float*)(ws + 6*S + 524288);
  float* aVall = vec;                         // [2][256]
  float* bVall = vec + 512;
  float* aWall = vec + 1024;
  float* bWall = vec + 1536;
  u16*   wm    = (u16*)(vec + 10240);         // 256x256 bf16 = 128KB (M^T weight)
  float* g     = vec + 43008;                 // [256]
  float* c2all = vec + 43264;                 // [2][65536] fp32

  char* douts = (char*)d_out;                 // d_out = 128MB; scratch dead before z writes
  u16* Vt1 = (u16*)douts;                     // [0,32MB)   read by attn
  u16* Vt2 = (u16*)(douts + S);               // [32,64MB)
  u16* O1  = (u16*)(douts + 2*S);             // [64,96MB)  written by attn, read by conv1
  u16* O2  = (u16*)(douts + 3*S);             // [96,128MB)
  float* c2p   = (float*)douts;               // [0,2MB)  xpose partials, dead before qkv
  float* vpsum = (float*)(douts + 2*S);       // [64,68MB) qkv V partials, dead before attn O1
  float* vpsq  = vpsum + 1048576;             // [68,72MB)
  float* upsum = (float*)douts;               // [0,2MB)  reused again after attn
  float* upsq  = upsum + 524288;              // [2,4MB)
  float* z = (float*)d_out;

  dim3 gt(1024, 4, 2);
  dim3 gcr(256, 2);
  dim3 gv2(256, 2);
  dim3 gu2(256, 2);

  k_wcvt<<<256, 256, 0, stream>>>(Qw, Kw, Vw, Ww, wb);
  k_g<<<1, 256, 0, stream>>>(Qb, Kw, g);
  k_mg<<<256, 256, 0, stream>>>(wb, wm);
  k_xpose<<<gt, 256, 0, stream>>>(x1, x2, xr1, xr2, g, c2p);
  k_c2red<<<gcr, 256, 0, stream>>>(c2p, c2all);
  k_qkv<<<8192, 256, 0, stream>>>(xr1, xr2, wb, wm, Vb, XM1, Vt1, XM2, Vt2, vpsum, vpsq);
  k_vstat2<<<gv2, 256, 0, stream>>>(vpsum, vpsq, Vg, Vbe, aVall, bVall);
  k_attn<<<2048, 256, 0, stream>>>(XM1, xr2, Vt2, XM2, xr1, Vt1, aVall, bVall, c2all, O1, O2);
  k_conv1<<<2048, 256, 0, stream>>>(O1, O2, wb + 196608, Wb, u1, u2, upsum, upsq);
  k_ustat2<<<gu2, 256, 0, stream>>>(upsum, upsq, Wg, Wbe, aWall, bWall);
  k_final<<<gt, 256, 0, stream>>>(u1, u2, xr1, xr2, aWall, bWall, z);
}